// Round 14
// baseline (448.627 us; speedup 1.0000x reference)
//
#include <hip/hip_runtime.h>
#include <hip/hip_bf16.h>

using bf16 = __hip_bfloat16;
typedef short s16x8 __attribute__((ext_vector_type(8)));
typedef short s16x4 __attribute__((ext_vector_type(4)));
typedef float f32x4 __attribute__((ext_vector_type(4)));
typedef float f32x2 __attribute__((ext_vector_type(2)));

#define BSZ   8
#define NN    15135
#define FF    64
#define GG    73
#define HH    256
#define EE    242160
#define K1P   192                 // 137 padded to mult of 64 (BK=64 gemm)
#define MREAL (BSZ * NN)          // 121080
#define MPAD  (946 * 128)         // 121088
#define HFC   512
#define NCHUNK 64
#define NCHUNKS ((NN + NCHUNK - 1) / NCHUNK)   // 237
// fp8 pre-scale: hw stored as e4m3(64*v); x64 folded into WT, 1/64 into csr_norm & dinv
#define FP8_INV_SCALE 0.015625f

#define GLOAD_LDS16(gp, lp)                                                     \
    __builtin_amdgcn_global_load_lds(                                           \
        (const __attribute__((address_space(1))) void*)(gp),                    \
        (__attribute__((address_space(3))) void*)(lp), 16, 0, 0)

// Column permutation applied to the 256-wide GEMM output space.
// Epilogue stores col c at byte position sigma(c) = (c&192) + 4*(c&15) + ((c>>4)&3);
// colmap(p) = sigma^-1(p). Aggregation is element-wise over rows, so a uniform
// column permutation commutes with it; consumers compensate via colmap.
__device__ __forceinline__ int colmap(int p) {
    return (p & 192) | ((p & 3) << 4) | ((p >> 2) & 15);
}

// ------------------------------------------------- fused prep: h0 | WT | zeros
// Zeroes deg counters, csr local counters, g accumulator, sync area.
#define PREP_H0_CNT (MREAL * (K1P / 8))
#define PREP_W1_CNT (256 * K1P)
#define PREP_W23_CNT 65536
#define PREP_TOT (PREP_H0_CNT + PREP_W1_CNT + 2 * PREP_W23_CNT + 2 * NN + MREAL + 1024)
__global__ void k_prep(const float* __restrict__ x, const float* __restrict__ gl,
                       bf16* __restrict__ h0,
                       const float* __restrict__ W1, const float* __restrict__ W2,
                       const float* __restrict__ W3, bf16* __restrict__ W1T,
                       bf16* __restrict__ W2T, bf16* __restrict__ W3T,
                       int* __restrict__ cnt, int* __restrict__ cnt2,
                       float* __restrict__ g, int* __restrict__ sync) {
    int idx = blockIdx.x * blockDim.x + threadIdx.x;
    if (idx < PREP_H0_CNT) {
        int m = idx / (K1P / 8);
        int q = idx - m * (K1P / 8);
        int j0 = q * 8;
        int n = m % NN;
        s16x8 o;
        #pragma unroll
        for (int k = 0; k < 8; ++k) {
            int j = j0 + k;
            float val;
            if (j < FF) val = x[(size_t)m * FF + j];
            else if (j < FF + GG) val = gl[(size_t)n * GG + (j - FF)];
            else val = 0.f;
            o[k] = (short)__bfloat16_as_ushort(__float2bfloat16(val));
        }
        *(s16x8*)&h0[(size_t)m * K1P + j0] = o;
        return;
    }
    idx -= PREP_H0_CNT;
    if (idx < PREP_W1_CNT) {
        int nn = idx / K1P, kk = idx - nn * K1P;
        W1T[idx] = __float2bfloat16(
            kk < FF + GG ? 64.f * W1[(size_t)kk * 256 + nn] : 0.f);
        return;
    }
    idx -= PREP_W1_CNT;
    if (idx < PREP_W23_CNT) {
        int nn = idx >> 8, kk = idx & 255;
        W2T[idx] = __float2bfloat16(64.f * W2[(size_t)colmap(kk) * 256 + nn]);
        return;
    }
    idx -= PREP_W23_CNT;
    if (idx < PREP_W23_CNT) {
        int nn = idx >> 8, kk = idx & 255;
        W3T[idx] = __float2bfloat16(64.f * W3[(size_t)colmap(kk) * 256 + nn]);
        return;
    }
    idx -= PREP_W23_CNT;
    if (idx < NN) { cnt[idx] = 0; return; }
    idx -= NN;
    if (idx < NN) { cnt2[idx] = 0; return; }
    idx -= NN;
    if (idx < MREAL) { g[idx] = 0.f; return; }
    idx -= MREAL;
    if (idx < 1024) sync[idx] = 0;
}

// ------------------------------------------- fused setup: deg+scan+csr
// 240 blocks x 1024 threads; ONE grid barrier (hierarchical: 8 group counters
// on separate cachelines, 30 arrivals each in parallel, then 8 root RMWs --
// the flat 240-RMW-one-line arrive measured ~15us/barrier in R8/R9).
#define NB_SETUP 240
#define TS 1024
__device__ __forceinline__ void gbar_once(int* sync) {
    __syncthreads();
    if (threadIdx.x == 0) {
        __threadfence();
        int grp = blockIdx.x & 7;                     // 30 blocks per group
        int old = atomicAdd(&sync[16 * (grp + 1)], 1);
        if (old == 29) atomicAdd(&sync[0], 1);
        while (__hip_atomic_load(&sync[0], __ATOMIC_RELAXED,
                                 __HIP_MEMORY_SCOPE_AGENT) < 8)
            __builtin_amdgcn_s_sleep(2);
        __threadfence();
    }
    __syncthreads();
}

__global__ __launch_bounds__(1024)
void k_setup(const int* __restrict__ erow, const int* __restrict__ ecol,
             int* __restrict__ cnt, int* __restrict__ offs,
             int* __restrict__ cnt2, int2* __restrict__ cpack,
             int* __restrict__ sync) {
    __shared__ int soffs[NN + 1];                     // 60.5 KB
    __shared__ int wtot[16], wpre[16];
    const int tid = threadIdx.x, bid = blockIdx.x;
    const int gid = bid * TS + tid;
    const int lane = tid & 63, w = tid >> 6;

    // phase 1: histogram; cache edge endpoints for phase 3
    int myc = 0, myr = 0;
    if (gid < EE) {
        myc = ecol[gid];
        myr = erow[gid];
        atomicAdd(&cnt[myc], 1);
    }
    gbar_once(sync);

    // phase 2: block-local exclusive scan of cnt[0..NN] into soffs
    {
        const int base = w * 946;                     // 16*946 = 15136 = NN+1
        int carry = 0;
        #pragma unroll
        for (int j = 0; j < 15; ++j) {                // 15*64=960 >= 946
            int o = j * 64 + lane;
            int i = base + o;
            bool in = o < 946;
            int v = (in && i < NN) ? cnt[i] : 0;
            int s = v;
            #pragma unroll
            for (int off = 1; off < 64; off <<= 1) {
                int t = __shfl_up(s, off);
                if (lane >= off) s += t;
            }
            if (in) soffs[i] = carry + s - v;         // exclusive
            carry += __shfl(s, 63);
        }
        if (lane == 0) wtot[w] = carry;
    }
    __syncthreads();
    if (w == 0 && lane < 16) {
        int t = wtot[lane];
        int s = t;
        #pragma unroll
        for (int off = 1; off < 16; off <<= 1) {
            int u = __shfl_up(s, off);
            if (lane >= off) s += u;
        }
        wpre[lane] = s - t;                           // exclusive over waves
    }
    __syncthreads();
    {
        const int base = w * 946;
        int add = wpre[w];
        if (add) {
            #pragma unroll
            for (int j = 0; j < 15; ++j) {
                int o = j * 64 + lane;
                if (o < 946) soffs[base + o] += add;
            }
        }
    }
    __syncthreads();

    // block 0 publishes offs for k_agg (kernel boundary handles coherence)
    if (bid == 0)
        for (int i = tid; i <= NN; i += TS) offs[i] = soffs[i];

    // phase 3: CSR fill from LDS offsets; norm from degree diffs
    if (gid < EE) {
        int bc = soffs[myc], dc = soffs[myc + 1] - bc;
        int br = soffs[myr], dr = soffs[myr + 1] - br;
        (void)br;
        int p = atomicAdd(&cnt2[myc], 1);
        float norm = rsqrtf((float)(dr + 1)) * rsqrtf((float)(dc + 1))
                     * FP8_INV_SCALE;
        cpack[bc + p] = make_int2(myr, __float_as_int(norm));
    }
}

// ---------------------------------------------------------------- MFMA GEMM
// BM=64 x BN=256, BK=64 via TWIN buffers (FROZEN since R13: neutral vs BK=32;
// barrier savings offset by occupancy, kept as measured baseline).
// C (fp8, x64 via pre-scaled WT): [row][256] sigma-layout, packed dword stores.
template <int K>
__global__ __launch_bounds__(256)
void k_gemm(const bf16* __restrict__ A, const bf16* __restrict__ BT,
            unsigned char* __restrict__ C) {
    __shared__ __align__(16) short As0[64 * 32], As1[64 * 32];    // 4+4 KB
    __shared__ __align__(16) short Bs0[256 * 32], Bs1[256 * 32];  // 16+16 KB
    const int tid  = threadIdx.x;
    const int bm   = blockIdx.x * 64;
    const int lane = tid & 63, wave = tid >> 6;
    const int wn   = wave * 64;
    const int fr   = lane & 15, quad = lane >> 4;
    const int r    = tid >> 2;           // 0..63
    const int c    = (tid & 3) * 8;      // shorts: 0,8,16,24

    const bf16* Ap = A  + (size_t)(bm + r) * K + c;
    const bf16* Bp = BT + (size_t)r * K + c;        // rows 0..63 (quarter 0)
    short* As0T = As0 + tid * 8;
    short* As1T = As1 + tid * 8;
    short* Bs0T = Bs0 + tid * 8;
    short* Bs1T = Bs1 + tid * 8;

    f32x4 acc[4][4] = {};

    for (int k0 = 0; k0 < K; k0 += 64) {
        GLOAD_LDS16(Ap + k0,      As0T);
        GLOAD_LDS16(Ap + k0 + 32, As1T);
        #pragma unroll
        for (int q = 0; q < 4; ++q) {
            GLOAD_LDS16(Bp + (size_t)(q * 64) * K + k0,      Bs0T + q * 64 * 32);
            GLOAD_LDS16(Bp + (size_t)(q * 64) * K + k0 + 32, Bs1T + q * 64 * 32);
        }
        __syncthreads();
        // slice 0
        {
            s16x8 af[4], bfv[4];
            #pragma unroll
            for (int i = 0; i < 4; ++i)
                af[i] = *(const s16x8*)&As0[(i * 16 + fr) * 32 + quad * 8];
            #pragma unroll
            for (int j = 0; j < 4; ++j)
                bfv[j] = *(const s16x8*)&Bs0[(wn + j * 16 + fr) * 32 + quad * 8];
            #pragma unroll
            for (int i = 0; i < 4; ++i)
                #pragma unroll
                for (int j = 0; j < 4; ++j)
                    acc[i][j] = __builtin_amdgcn_mfma_f32_16x16x32_bf16(
                        af[i], bfv[j], acc[i][j], 0, 0, 0);
        }
        // slice 1
        {
            s16x8 af[4], bfv[4];
            #pragma unroll
            for (int i = 0; i < 4; ++i)
                af[i] = *(const s16x8*)&As1[(i * 16 + fr) * 32 + quad * 8];
            #pragma unroll
            for (int j = 0; j < 4; ++j)
                bfv[j] = *(const s16x8*)&Bs1[(wn + j * 16 + fr) * 32 + quad * 8];
            #pragma unroll
            for (int i = 0; i < 4; ++i)
                #pragma unroll
                for (int j = 0; j < 4; ++j)
                    acc[i][j] = __builtin_amdgcn_mfma_f32_16x16x32_bf16(
                        af[i], bfv[j], acc[i][j], 0, 0, 0);
        }
        __syncthreads();
    }

    // epilogue: packed dword store per row (sigma-layout); x64 already in WT
    #pragma unroll
    for (int i = 0; i < 4; ++i) {
        int rbase = bm + i * 16 + quad * 4;
        #pragma unroll
        for (int rr = 0; rr < 4; ++rr) {
            int row = rbase + rr;
            if (row >= MREAL) continue;
            unsigned wpack = (unsigned)__builtin_amdgcn_cvt_pk_fp8_f32(
                acc[i][0][rr], acc[i][1][rr], 0, false);
            wpack = (unsigned)__builtin_amdgcn_cvt_pk_fp8_f32(
                acc[i][2][rr], acc[i][3][rr], (int)wpack, true);
            *(unsigned*)&C[(size_t)row * 256 + wn + fr * 4] = wpack;
        }
    }
}

// ------------------------------------------------------- aggregate + elu + fc
// hw fp8 [b*NN+n][256] (x64, sigma-layout); hout bf16 [b*NN+n][256] (sigma).
// Batch-partitioned for XCD L2 residency (blockIdx%8 -> XCD).
// DUAL-NODE interleave: each wave processes a node PAIR (va, va+1) with a
// joint 8-group gather loop -> 2 independent cpack->gather->FMA latency
// chains per wave (single-group nodes at avg deg 16 have no intra-node
// pipelining; cross-node is the only ILP source). VGPR ~80 -> bounds (256,4).
#define AGG_GRP 1024
#define AGG_STRIDE (AGG_GRP * 4)          // 4096 waves per batch

__device__ __forceinline__ void edge_fma(unsigned qv, float mv,
                                         f32x2& a01, f32x2& a23) {
    f32x2 t0 = __builtin_amdgcn_cvt_pk_f32_fp8(qv, false);
    f32x2 t1 = __builtin_amdgcn_cvt_pk_f32_fp8(qv, true);
    f32x2 mm = {mv, mv};
    a01 += mm * t0;
    a23 += mm * t1;
}

__device__ __forceinline__ void agg_drain(const unsigned char* hwb,
                                          const int2* __restrict__ cpack,
                                          unsigned c4, int e, int end,
                                          f32x2& a01, f32x2& a23) {
    while (e + 8 <= end) {
        int2 ep[8];
        #pragma unroll
        for (int u = 0; u < 8; ++u) ep[u] = cpack[e + u];
        unsigned q[8];
        #pragma unroll
        for (int u = 0; u < 8; ++u)
            q[u] = *(const unsigned*)(hwb + (((unsigned)ep[u].x) << 8) + c4);
        #pragma unroll
        for (int u = 0; u < 8; ++u)
            edge_fma(q[u], __int_as_float(ep[u].y), a01, a23);
        e += 8;
    }
    if (e + 4 <= end) {
        int2 ep[4];
        #pragma unroll
        for (int u = 0; u < 4; ++u) ep[u] = cpack[e + u];
        unsigned q[4];
        #pragma unroll
        for (int u = 0; u < 4; ++u)
            q[u] = *(const unsigned*)(hwb + (((unsigned)ep[u].x) << 8) + c4);
        #pragma unroll
        for (int u = 0; u < 4; ++u)
            edge_fma(q[u], __int_as_float(ep[u].y), a01, a23);
        e += 4;
    }
    if (e + 2 <= end) {
        int2 ep0 = cpack[e], ep1 = cpack[e + 1];
        unsigned q0 = *(const unsigned*)(hwb + (((unsigned)ep0.x) << 8) + c4);
        unsigned q1 = *(const unsigned*)(hwb + (((unsigned)ep1.x) << 8) + c4);
        edge_fma(q0, __int_as_float(ep0.y), a01, a23);
        edge_fma(q1, __int_as_float(ep1.y), a01, a23);
        e += 2;
    }
    if (e < end) {
        int2 ep0 = cpack[e];
        unsigned q0 = *(const unsigned*)(hwb + (((unsigned)ep0.x) << 8) + c4);
        edge_fma(q0, __int_as_float(ep0.y), a01, a23);
    }
}

__global__ __launch_bounds__(256, 4)
void k_agg(const unsigned char* __restrict__ hw, bf16* __restrict__ hout,
           const int* __restrict__ offs, const int2* __restrict__ cpack,
           const float* __restrict__ bias, const float* __restrict__ fcW,
           float* __restrict__ g, int writeH) {
    const int b    = blockIdx.x & 7;
    const int grp  = blockIdx.x >> 3;          // 0..AGG_GRP-1
    const int wid  = threadIdx.x >> 6;         // 0..3
    const int lane = threadIdx.x & 63;
    const int wv   = grp * 4 + wid;            // 0..AGG_STRIDE-1
    const unsigned c4 = lane * 4;

    const unsigned char* hwb = hw + (size_t)b * NN * 256;

    float bias4[4], fw4[4];
    #pragma unroll
    for (int k = 0; k < 4; ++k) {
        int cl = colmap((int)c4 + k);
        bias4[k] = bias[cl];
        fw4[k]   = fcW[3 * cl];
    }

    for (int p0 = wv * 2; p0 < NN; p0 += 2 * AGG_STRIDE) {
        const int va   = __builtin_amdgcn_readfirstlane(p0);
        const int hasB = (va + 1 < NN);
        const int beg_a = __builtin_amdgcn_readfirstlane(offs[va]);
        const int end_a = __builtin_amdgcn_readfirstlane(offs[va + 1]);
        const int beg_b = end_a;
        const int end_b = hasB ? __builtin_amdgcn_readfirstlane(offs[va + 2])
                               : end_a;
        const float dia = FP8_INV_SCALE / (float)(end_a - beg_a + 1);
        const float dib = FP8_INV_SCALE / (float)(end_b - beg_b + 1);

        f32x2 a01a, a23a, a01b = {0.f, 0.f}, a23b = {0.f, 0.f};
        {
            unsigned qa = *(const unsigned*)(hwb + (((unsigned)va) << 8) + c4);
            f32x2 t0 = __builtin_amdgcn_cvt_pk_f32_fp8(qa, false);
            f32x2 t1 = __builtin_amdgcn_cvt_pk_f32_fp8(qa, true);
            f32x2 dd = {dia, dia};
            a01a = dd * t0;
            a23a = dd * t1;
        }
        if (hasB) {
            unsigned qb = *(const unsigned*)(hwb + (((unsigned)(va + 1)) << 8) + c4);
            f32x2 t0 = __builtin_amdgcn_cvt_pk_f32_fp8(qb, false);
            f32x2 t1 = __builtin_amdgcn_cvt_pk_f32_fp8(qb, true);
            f32x2 dd = {dib, dib};
            a01b = dd * t0;
            a23b = dd * t1;
        }

        // joint loop: both nodes' metadata + gathers in flight together
        int ea = beg_a, eb = beg_b;
        while (ea + 8 <= end_a && eb + 8 <= end_b) {
            int2 epa[8], epb[8];
            #pragma unroll
            for (int u = 0; u < 8; ++u) epa[u] = cpack[ea + u];
            #pragma unroll
            for (int u = 0; u < 8; ++u) epb[u] = cpack[eb + u];
            unsigned qa[8], qb[8];
            #pragma unroll
            for (int u = 0; u < 8; ++u)
                qa[u] = *(const unsigned*)(hwb + (((unsigned)epa[u].x) << 8) + c4);
            #pragma unroll
            for (int u = 0; u < 8; ++u)
                qb[u] = *(const unsigned*)(hwb + (((unsigned)epb[u].x) << 8) + c4);
            #pragma unroll
            for (int u = 0; u < 8; ++u)
                edge_fma(qa[u], __int_as_float(epa[u].y), a01a, a23a);
            #pragma unroll
            for (int u = 0; u < 8; ++u)
                edge_fma(qb[u], __int_as_float(epb[u].y), a01b, a23b);
            ea += 8;
            eb += 8;
        }
        agg_drain(hwb, cpack, c4, ea, end_a, a01a, a23a);
        if (hasB) agg_drain(hwb, cpack, c4, eb, end_b, a01b, a23b);

        // epilogue node A
        {
            float acc4[4] = {a01a[0], a01a[1], a23a[0], a23a[1]};
            float p = 0.f;
            s16x4 o4;
            #pragma unroll
            for (int k = 0; k < 4; ++k) {
                float hv = acc4[k] + bias4[k];
                hv = hv > 0.f ? hv : (__expf(hv) - 1.0f);
                o4[k] = (short)__bfloat16_as_ushort(__float2bfloat16(hv));
                p += hv * fw4[k];
            }
            if (writeH) {
                s16x4* dst = (s16x4*)&hout[((size_t)b * NN + va) * 256 + c4];
                __builtin_nontemporal_store(o4, dst);
            }
            #pragma unroll
            for (int off = 32; off; off >>= 1) p += __shfl_xor(p, off);
            if (lane == 0) g[(size_t)b * NN + va] += p;
        }
        // epilogue node B
        if (hasB) {
            float acc4[4] = {a01b[0], a01b[1], a23b[0], a23b[1]};
            float p = 0.f;
            s16x4 o4;
            #pragma unroll
            for (int k = 0; k < 4; ++k) {
                float hv = acc4[k] + bias4[k];
                hv = hv > 0.f ? hv : (__expf(hv) - 1.0f);
                o4[k] = (short)__bfloat16_as_ushort(__float2bfloat16(hv));
                p += hv * fw4[k];
            }
            if (writeH) {
                s16x4* dst = (s16x4*)&hout[((size_t)b * NN + va + 1) * 256 + c4];
                __builtin_nontemporal_store(o4, dst);
            }
            #pragma unroll
            for (int off = 32; off; off >>= 1) p += __shfl_xor(p, off);
            if (lane == 0) g[(size_t)b * NN + va + 1] += p;
        }
    }
}

// ------------------------------------------------------------ lin1 partials
__global__ __launch_bounds__(256)
void k_lin1(const float* __restrict__ g, const float* __restrict__ fcb,
            const float* __restrict__ W, float* __restrict__ zpart) {
    const int ny = blockIdx.x;
    const int n0 = ny * NCHUNK;
    const int cnt = min(NCHUNK, NN - n0);
    const int tid = threadIdx.x;
    __shared__ float sg[8][NCHUNK];
    float fb = fcb[0];
    for (int idx = tid; idx < 8 * NCHUNK; idx += 256) {
        int b = idx / NCHUNK, nn = idx - b * NCHUNK;
        sg[b][nn] = (nn < cnt) ? (g[(size_t)b * NN + n0 + nn] + fb) : 0.f;
    }
    __syncthreads();
    float2 acc[8] = {};
    for (int nn = 0; nn < cnt; ++nn) {
        float2 w = *(const float2*)&W[(size_t)(n0 + nn) * HFC + tid * 2];
        #pragma unroll
        for (int b = 0; b < 8; ++b) {
            float gv = sg[b][nn];
            acc[b].x += gv * w.x;
            acc[b].y += gv * w.y;
        }
    }
    #pragma unroll
    for (int b = 0; b < 8; ++b)
        *(float2*)&zpart[(size_t)ny * 4096 + b * 512 + tid * 2] = acc[b];
}

// ----------------------------- lin1 reduce + lin2 + log_softmax (one launch)
// 8 blocks (one per batch) x 512 threads.
__global__ __launch_bounds__(512)
void k_lin2(const float* __restrict__ zpart, const float* __restrict__ l1b,
            const float* __restrict__ W2, const float* __restrict__ l2b,
            float* __restrict__ out) {
    __shared__ float r0[512], r1[512];
    const int b = blockIdx.x, t = threadIdx.x;
    float s = 0.f;
    for (int c = 0; c < NCHUNKS; ++c) s += zpart[(size_t)c * 4096 + b * 512 + t];
    float zv = s + l1b[t];
    zv = zv > 0.f ? zv : (__expf(zv) - 1.0f);
    r0[t] = zv * W2[t * 2 + 0];
    r1[t] = zv * W2[t * 2 + 1];
    __syncthreads();
    for (int st = 256; st; st >>= 1) {
        if (t < st) { r0[t] += r0[t + st]; r1[t] += r1[t + st]; }
        __syncthreads();
    }
    if (t == 0) {
        float o0 = r0[0] + l2b[0], o1 = r1[0] + l2b[1];
        float m = fmaxf(o0, o1);
        float lse = m + logf(expf(o0 - m) + expf(o1 - m));
        out[b * 2 + 0] = o0 - lse;
        out[b * 2 + 1] = o1 - lse;
    }
}

// ---------------------------------------------------------------- launcher
extern "C" void kernel_launch(void* const* d_in, const int* in_sizes, int n_in,
                              void* d_out, int out_size, void* d_ws, size_t ws_size,
                              hipStream_t stream) {
    const float* x    = (const float*)d_in[0];
    const int*   eidx = (const int*)d_in[2];      // [0..E) = row, [E..2E) = col
    const float* gl   = (const float*)d_in[3];
    const float* W1   = (const float*)d_in[4];
    const float* b1   = (const float*)d_in[5];
    const float* W2   = (const float*)d_in[6];
    const float* b2   = (const float*)d_in[7];
    const float* W3   = (const float*)d_in[8];
    const float* b3   = (const float*)d_in[9];
    const float* fcW  = (const float*)d_in[10];
    const float* fcb  = (const float*)d_in[11];
    const float* l1W  = (const float*)d_in[12];
    const float* l1b  = (const float*)d_in[13];
    const float* l2W  = (const float*)d_in[14];
    const float* l2b  = (const float*)d_in[15];
    float* out = (float*)d_out;

    size_t off = 0;
    auto alloc = [&](size_t bytes) {
        void* p = (char*)d_ws + off;
        off += (bytes + 255) & ~(size_t)255;
        return p;
    };
    bf16* bufA          = (bf16*)alloc((size_t)MPAD * 256 * 2);          // 62 MB
    unsigned char* bufC = (unsigned char*)alloc((size_t)MPAD * 256);     // 31 MB
    bf16* W1T      = (bf16*)alloc(256 * K1P * 2);
    bf16* W2T      = (bf16*)alloc(256 * 256 * 2);
    bf16* W3T      = (bf16*)alloc(256 * 256 * 2);
    int*  deg_cnt  = (int*)alloc(NN * 4);
    int*  offs     = (int*)alloc((NN + 1) * 4);
    int*  cnt2     = (int*)alloc(NN * 4);
    int2* cpack    = (int2*)alloc((size_t)EE * 8);
    float* g       = (float*)alloc((size_t)BSZ * NN * 4);
    int*  sync     = (int*)alloc(1024 * 4);

    // zpart aliases bufC: dead after the last k_agg
    float* zpart = (float*)bufC;                              // 3.9 MB

    const int* erow = eidx;
    const int* ecol = eidx + EE;

    // 1. fused prep (h0, WT x3, zero cnt/cnt2/g/sync)
    k_prep<<<(PREP_TOT + 255) / 256, 256, 0, stream>>>(
        x, gl, bufA, W1, W2, W3, W1T, W2T, W3T, deg_cnt, cnt2, g, sync);

    // 2. fused setup (deg + redundant LDS scan + csr), 1 hierarchical barrier
    k_setup<<<NB_SETUP, TS, 0, stream>>>(erow, ecol, deg_cnt, offs, cnt2,
                                         cpack, sync);

    dim3 ggrid(MPAD / 64);
    dim3 agrid(8 * AGG_GRP);

    // layer 1
    k_gemm<K1P><<<ggrid, 256, 0, stream>>>(bufA, W1T, bufC);
    k_agg<<<agrid, 256, 0, stream>>>(bufC, bufA, offs, cpack,
                                     b1, fcW + 0, g, 1);
    // layer 2
    k_gemm<256><<<ggrid, 256, 0, stream>>>(bufA, W2T, bufC);
    k_agg<<<agrid, 256, 0, stream>>>(bufC, bufA, offs, cpack,
                                     b2, fcW + 1, g, 1);
    // layer 3 (h3 not materialized; only fc contribution)
    k_gemm<256><<<ggrid, 256, 0, stream>>>(bufA, W3T, bufC);
    k_agg<<<agrid, 256, 0, stream>>>(bufC, bufA, offs, cpack,
                                     b3, fcW + 2, g, 0);

    k_lin1<<<NCHUNKS, 256, 0, stream>>>(g, fcb, l1W, zpart);
    k_lin2<<<8, 512, 0, stream>>>(zpart, l1b, l2W, l2b, out);
}

// Round 15
// 448.564 us; speedup vs baseline: 1.0001x; 1.0001x over previous
//
#include <hip/hip_runtime.h>
#include <hip/hip_bf16.h>

using bf16 = __hip_bfloat16;
typedef short s16x8 __attribute__((ext_vector_type(8)));
typedef short s16x4 __attribute__((ext_vector_type(4)));
typedef float f32x4 __attribute__((ext_vector_type(4)));
typedef float f32x2 __attribute__((ext_vector_type(2)));

#define BSZ   8
#define NN    15135
#define FF    64
#define GG    73
#define HH    256
#define EE    242160
#define K1P   192                 // 137 padded to mult of 64 (BK=64 gemm)
#define MREAL (BSZ * NN)          // 121080
#define MPAD  (946 * 128)         // 121088
#define HFC   512
#define NCHUNK 64
#define NCHUNKS ((NN + NCHUNK - 1) / NCHUNK)   // 237
// fp8 pre-scale: hw stored as e4m3(64*v); x64 folded into WT, 1/64 into csr_norm & dinv
#define FP8_INV_SCALE 0.015625f

#define GLOAD_LDS16(gp, lp)                                                     \
    __builtin_amdgcn_global_load_lds(                                           \
        (const __attribute__((address_space(1))) void*)(gp),                    \
        (__attribute__((address_space(3))) void*)(lp), 16, 0, 0)

// Column permutation applied to the 256-wide GEMM output space.
// Epilogue stores col c at byte position sigma(c) = (c&192) + 4*(c&15) + ((c>>4)&3);
// colmap(p) = sigma^-1(p). Aggregation is element-wise over rows, so a uniform
// column permutation commutes with it; consumers compensate via colmap.
__device__ __forceinline__ int colmap(int p) {
    return (p & 192) | ((p & 3) << 4) | ((p >> 2) & 15);
}

// ------------------------------------------------- fused prep: h0 | WT | zeros
// Zeroes deg counters, csr local counters, g accumulator, sync area.
#define PREP_H0_CNT (MREAL * (K1P / 8))
#define PREP_W1_CNT (256 * K1P)
#define PREP_W23_CNT 65536
#define PREP_TOT (PREP_H0_CNT + PREP_W1_CNT + 2 * PREP_W23_CNT + 2 * NN + MREAL + 1024)
__global__ void k_prep(const float* __restrict__ x, const float* __restrict__ gl,
                       bf16* __restrict__ h0,
                       const float* __restrict__ W1, const float* __restrict__ W2,
                       const float* __restrict__ W3, bf16* __restrict__ W1T,
                       bf16* __restrict__ W2T, bf16* __restrict__ W3T,
                       int* __restrict__ cnt, int* __restrict__ cnt2,
                       float* __restrict__ g, int* __restrict__ sync) {
    int idx = blockIdx.x * blockDim.x + threadIdx.x;
    if (idx < PREP_H0_CNT) {
        int m = idx / (K1P / 8);
        int q = idx - m * (K1P / 8);
        int j0 = q * 8;
        int n = m % NN;
        s16x8 o;
        #pragma unroll
        for (int k = 0; k < 8; ++k) {
            int j = j0 + k;
            float val;
            if (j < FF) val = x[(size_t)m * FF + j];
            else if (j < FF + GG) val = gl[(size_t)n * GG + (j - FF)];
            else val = 0.f;
            o[k] = (short)__bfloat16_as_ushort(__float2bfloat16(val));
        }
        *(s16x8*)&h0[(size_t)m * K1P + j0] = o;
        return;
    }
    idx -= PREP_H0_CNT;
    if (idx < PREP_W1_CNT) {
        int nn = idx / K1P, kk = idx - nn * K1P;
        W1T[idx] = __float2bfloat16(
            kk < FF + GG ? 64.f * W1[(size_t)kk * 256 + nn] : 0.f);
        return;
    }
    idx -= PREP_W1_CNT;
    if (idx < PREP_W23_CNT) {
        int nn = idx >> 8, kk = idx & 255;
        W2T[idx] = __float2bfloat16(64.f * W2[(size_t)colmap(kk) * 256 + nn]);
        return;
    }
    idx -= PREP_W23_CNT;
    if (idx < PREP_W23_CNT) {
        int nn = idx >> 8, kk = idx & 255;
        W3T[idx] = __float2bfloat16(64.f * W3[(size_t)colmap(kk) * 256 + nn]);
        return;
    }
    idx -= PREP_W23_CNT;
    if (idx < NN) { cnt[idx] = 0; return; }
    idx -= NN;
    if (idx < NN) { cnt2[idx] = 0; return; }
    idx -= NN;
    if (idx < MREAL) { g[idx] = 0.f; return; }
    idx -= MREAL;
    if (idx < 1024) sync[idx] = 0;
}

// ------------------------------------------- fused setup: deg+scan+csr
// 240 blocks x 1024 threads; ONE grid barrier (hierarchical: 8 group counters
// on separate cachelines, 30 arrivals each in parallel, then 8 root RMWs --
// the flat 240-RMW-one-line arrive measured ~15us/barrier in R8/R9).
#define NB_SETUP 240
#define TS 1024
__device__ __forceinline__ void gbar_once(int* sync) {
    __syncthreads();
    if (threadIdx.x == 0) {
        __threadfence();
        int grp = blockIdx.x & 7;                     // 30 blocks per group
        int old = atomicAdd(&sync[16 * (grp + 1)], 1);
        if (old == 29) atomicAdd(&sync[0], 1);
        while (__hip_atomic_load(&sync[0], __ATOMIC_RELAXED,
                                 __HIP_MEMORY_SCOPE_AGENT) < 8)
            __builtin_amdgcn_s_sleep(2);
        __threadfence();
    }
    __syncthreads();
}

__global__ __launch_bounds__(1024)
void k_setup(const int* __restrict__ erow, const int* __restrict__ ecol,
             int* __restrict__ cnt, int* __restrict__ offs,
             int* __restrict__ cnt2, int2* __restrict__ cpack,
             int* __restrict__ sync) {
    __shared__ int soffs[NN + 1];                     // 60.5 KB
    __shared__ int wtot[16], wpre[16];
    const int tid = threadIdx.x, bid = blockIdx.x;
    const int gid = bid * TS + tid;
    const int lane = tid & 63, w = tid >> 6;

    // phase 1: histogram; cache edge endpoints for phase 3
    int myc = 0, myr = 0;
    if (gid < EE) {
        myc = ecol[gid];
        myr = erow[gid];
        atomicAdd(&cnt[myc], 1);
    }
    gbar_once(sync);

    // phase 2: block-local exclusive scan of cnt[0..NN] into soffs
    {
        const int base = w * 946;                     // 16*946 = 15136 = NN+1
        int carry = 0;
        #pragma unroll
        for (int j = 0; j < 15; ++j) {                // 15*64=960 >= 946
            int o = j * 64 + lane;
            int i = base + o;
            bool in = o < 946;
            int v = (in && i < NN) ? cnt[i] : 0;
            int s = v;
            #pragma unroll
            for (int off = 1; off < 64; off <<= 1) {
                int t = __shfl_up(s, off);
                if (lane >= off) s += t;
            }
            if (in) soffs[i] = carry + s - v;         // exclusive
            carry += __shfl(s, 63);
        }
        if (lane == 0) wtot[w] = carry;
    }
    __syncthreads();
    if (w == 0 && lane < 16) {
        int t = wtot[lane];
        int s = t;
        #pragma unroll
        for (int off = 1; off < 16; off <<= 1) {
            int u = __shfl_up(s, off);
            if (lane >= off) s += u;
        }
        wpre[lane] = s - t;                           // exclusive over waves
    }
    __syncthreads();
    {
        const int base = w * 946;
        int add = wpre[w];
        if (add) {
            #pragma unroll
            for (int j = 0; j < 15; ++j) {
                int o = j * 64 + lane;
                if (o < 946) soffs[base + o] += add;
            }
        }
    }
    __syncthreads();

    // block 0 publishes offs for k_agg (kernel boundary handles coherence)
    if (bid == 0)
        for (int i = tid; i <= NN; i += TS) offs[i] = soffs[i];

    // phase 3: CSR fill from LDS offsets; norm from degree diffs
    if (gid < EE) {
        int bc = soffs[myc], dc = soffs[myc + 1] - bc;
        int br = soffs[myr], dr = soffs[myr + 1] - br;
        (void)br;
        int p = atomicAdd(&cnt2[myc], 1);
        float norm = rsqrtf((float)(dr + 1)) * rsqrtf((float)(dc + 1))
                     * FP8_INV_SCALE;
        cpack[bc + p] = make_int2(myr, __float_as_int(norm));
    }
}

// ---------------------------------------------------------------- MFMA GEMM
// BM=64 x BN=256, BK=64 via TWIN buffers (FROZEN since R13: neutral vs BK=32;
// barrier savings offset by occupancy, kept as measured baseline).
// C (fp8, x64 via pre-scaled WT): [row][256] sigma-layout, packed dword stores.
template <int K>
__global__ __launch_bounds__(256)
void k_gemm(const bf16* __restrict__ A, const bf16* __restrict__ BT,
            unsigned char* __restrict__ C) {
    __shared__ __align__(16) short As0[64 * 32], As1[64 * 32];    // 4+4 KB
    __shared__ __align__(16) short Bs0[256 * 32], Bs1[256 * 32];  // 16+16 KB
    const int tid  = threadIdx.x;
    const int bm   = blockIdx.x * 64;
    const int lane = tid & 63, wave = tid >> 6;
    const int wn   = wave * 64;
    const int fr   = lane & 15, quad = lane >> 4;
    const int r    = tid >> 2;           // 0..63
    const int c    = (tid & 3) * 8;      // shorts: 0,8,16,24

    const bf16* Ap = A  + (size_t)(bm + r) * K + c;
    const bf16* Bp = BT + (size_t)r * K + c;        // rows 0..63 (quarter 0)
    short* As0T = As0 + tid * 8;
    short* As1T = As1 + tid * 8;
    short* Bs0T = Bs0 + tid * 8;
    short* Bs1T = Bs1 + tid * 8;

    f32x4 acc[4][4] = {};

    for (int k0 = 0; k0 < K; k0 += 64) {
        GLOAD_LDS16(Ap + k0,      As0T);
        GLOAD_LDS16(Ap + k0 + 32, As1T);
        #pragma unroll
        for (int q = 0; q < 4; ++q) {
            GLOAD_LDS16(Bp + (size_t)(q * 64) * K + k0,      Bs0T + q * 64 * 32);
            GLOAD_LDS16(Bp + (size_t)(q * 64) * K + k0 + 32, Bs1T + q * 64 * 32);
        }
        __syncthreads();
        // slice 0
        {
            s16x8 af[4], bfv[4];
            #pragma unroll
            for (int i = 0; i < 4; ++i)
                af[i] = *(const s16x8*)&As0[(i * 16 + fr) * 32 + quad * 8];
            #pragma unroll
            for (int j = 0; j < 4; ++j)
                bfv[j] = *(const s16x8*)&Bs0[(wn + j * 16 + fr) * 32 + quad * 8];
            #pragma unroll
            for (int i = 0; i < 4; ++i)
                #pragma unroll
                for (int j = 0; j < 4; ++j)
                    acc[i][j] = __builtin_amdgcn_mfma_f32_16x16x32_bf16(
                        af[i], bfv[j], acc[i][j], 0, 0, 0);
        }
        // slice 1
        {
            s16x8 af[4], bfv[4];
            #pragma unroll
            for (int i = 0; i < 4; ++i)
                af[i] = *(const s16x8*)&As1[(i * 16 + fr) * 32 + quad * 8];
            #pragma unroll
            for (int j = 0; j < 4; ++j)
                bfv[j] = *(const s16x8*)&Bs1[(wn + j * 16 + fr) * 32 + quad * 8];
            #pragma unroll
            for (int i = 0; i < 4; ++i)
                #pragma unroll
                for (int j = 0; j < 4; ++j)
                    acc[i][j] = __builtin_amdgcn_mfma_f32_16x16x32_bf16(
                        af[i], bfv[j], acc[i][j], 0, 0, 0);
        }
        __syncthreads();
    }

    // epilogue: packed dword store per row (sigma-layout); x64 already in WT
    #pragma unroll
    for (int i = 0; i < 4; ++i) {
        int rbase = bm + i * 16 + quad * 4;
        #pragma unroll
        for (int rr = 0; rr < 4; ++rr) {
            int row = rbase + rr;
            if (row >= MREAL) continue;
            unsigned wpack = (unsigned)__builtin_amdgcn_cvt_pk_fp8_f32(
                acc[i][0][rr], acc[i][1][rr], 0, false);
            wpack = (unsigned)__builtin_amdgcn_cvt_pk_fp8_f32(
                acc[i][2][rr], acc[i][3][rr], (int)wpack, true);
            *(unsigned*)&C[(size_t)row * 256 + wn + fr * 4] = wpack;
        }
    }
}

// ------------------------------------------------------- aggregate + elu + fc
// hw fp8 [b*NN+n][256] (x64, sigma-layout); hout bf16 [b*NN+n][256] (sigma).
// Batch-partitioned for XCD L2 residency (blockIdx%8 -> XCD).
// R13 single-node structure (dual-node interleave REGRESSED in R14: -TLP).
// AGG_GRP 2048: ~1.85 nodes/wave -- finer granularity to shorten the
// degree-variance tail (occupancy was 68% with no resource limit).
#define AGG_GRP 2048
#define AGG_STRIDE (AGG_GRP * 4)          // 8192 waves per batch
__global__ __launch_bounds__(256, 8)
void k_agg(const unsigned char* __restrict__ hw, bf16* __restrict__ hout,
           const int* __restrict__ offs, const int2* __restrict__ cpack,
           const float* __restrict__ bias, const float* __restrict__ fcW,
           float* __restrict__ g, int writeH) {
    const int b    = blockIdx.x & 7;
    const int grp  = blockIdx.x >> 3;          // 0..AGG_GRP-1
    const int wid  = threadIdx.x >> 6;         // 0..3
    const int lane = threadIdx.x & 63;
    const int wv   = grp * 4 + wid;            // 0..AGG_STRIDE-1
    const unsigned c4 = lane * 4;

    const unsigned char* hwb = hw + (size_t)b * NN * 256;

    float bias4[4], fw4[4];
    #pragma unroll
    for (int k = 0; k < 4; ++k) {
        int cl = colmap((int)c4 + k);
        bias4[k] = bias[cl];
        fw4[k]   = fcW[3 * cl];
    }

    for (int v0 = wv; v0 < NN; v0 += AGG_STRIDE) {
        const int v   = __builtin_amdgcn_readfirstlane(v0);
        const int beg = __builtin_amdgcn_readfirstlane(offs[v]);
        const int end = __builtin_amdgcn_readfirstlane(offs[v + 1]);
        const float di = FP8_INV_SCALE / (float)(end - beg + 1);
        f32x2 a01, a23;
        {
            unsigned q = *(const unsigned*)(hwb + (((unsigned)v) << 8) + c4);
            f32x2 t0 = __builtin_amdgcn_cvt_pk_f32_fp8(q, false);
            f32x2 t1 = __builtin_amdgcn_cvt_pk_f32_fp8(q, true);
            f32x2 dd = {di, di};
            a01 = dd * t0;
            a23 = dd * t1;
        }

        #define EDGE1(qv, mv) {                                            \
            f32x2 t0 = __builtin_amdgcn_cvt_pk_f32_fp8((qv), false);       \
            f32x2 t1 = __builtin_amdgcn_cvt_pk_f32_fp8((qv), true);        \
            f32x2 mm = {(mv), (mv)};                                       \
            a01 += mm * t0;                                                \
            a23 += mm * t1; }

        int e = beg;
        while (e + 16 <= end) {
            int2 ep[16];
            #pragma unroll
            for (int u = 0; u < 16; ++u) ep[u] = cpack[e + u];
            unsigned q[16];
            #pragma unroll
            for (int u = 0; u < 16; ++u)
                q[u] = *(const unsigned*)(hwb + (((unsigned)ep[u].x) << 8) + c4);
            #pragma unroll
            for (int u = 0; u < 16; ++u) EDGE1(q[u], __int_as_float(ep[u].y));
            e += 16;
        }
        if (e + 8 <= end) {
            int2 ep[8];
            #pragma unroll
            for (int u = 0; u < 8; ++u) ep[u] = cpack[e + u];
            unsigned q[8];
            #pragma unroll
            for (int u = 0; u < 8; ++u)
                q[u] = *(const unsigned*)(hwb + (((unsigned)ep[u].x) << 8) + c4);
            #pragma unroll
            for (int u = 0; u < 8; ++u) EDGE1(q[u], __int_as_float(ep[u].y));
            e += 8;
        }
        if (e + 4 <= end) {
            int2 ep[4];
            #pragma unroll
            for (int u = 0; u < 4; ++u) ep[u] = cpack[e + u];
            unsigned q[4];
            #pragma unroll
            for (int u = 0; u < 4; ++u)
                q[u] = *(const unsigned*)(hwb + (((unsigned)ep[u].x) << 8) + c4);
            #pragma unroll
            for (int u = 0; u < 4; ++u) EDGE1(q[u], __int_as_float(ep[u].y));
            e += 4;
        }
        if (e + 2 <= end) {
            int2 ep0 = cpack[e], ep1 = cpack[e + 1];
            unsigned q0 = *(const unsigned*)(hwb + (((unsigned)ep0.x) << 8) + c4);
            unsigned q1 = *(const unsigned*)(hwb + (((unsigned)ep1.x) << 8) + c4);
            EDGE1(q0, __int_as_float(ep0.y));
            EDGE1(q1, __int_as_float(ep1.y));
            e += 2;
        }
        if (e < end) {
            int2 ep0 = cpack[e];
            unsigned q0 = *(const unsigned*)(hwb + (((unsigned)ep0.x) << 8) + c4);
            EDGE1(q0, __int_as_float(ep0.y));
        }
        #undef EDGE1

        float acc4[4] = {a01[0], a01[1], a23[0], a23[1]};
        float p = 0.f;
        s16x4 o4;
        #pragma unroll
        for (int k = 0; k < 4; ++k) {
            float hv = acc4[k] + bias4[k];
            hv = hv > 0.f ? hv : (__expf(hv) - 1.0f);
            o4[k] = (short)__bfloat16_as_ushort(__float2bfloat16(hv));
            p += hv * fw4[k];
        }
        if (writeH) {
            s16x4* dst = (s16x4*)&hout[((size_t)b * NN + v) * 256 + c4];
            __builtin_nontemporal_store(o4, dst);
        }

        #pragma unroll
        for (int off = 32; off; off >>= 1) p += __shfl_xor(p, off);
        if (lane == 0) g[(size_t)b * NN + v] += p;
    }
}

// ------------------------------------------------------------ lin1 partials
__global__ __launch_bounds__(256)
void k_lin1(const float* __restrict__ g, const float* __restrict__ fcb,
            const float* __restrict__ W, float* __restrict__ zpart) {
    const int ny = blockIdx.x;
    const int n0 = ny * NCHUNK;
    const int cnt = min(NCHUNK, NN - n0);
    const int tid = threadIdx.x;
    __shared__ float sg[8][NCHUNK];
    float fb = fcb[0];
    for (int idx = tid; idx < 8 * NCHUNK; idx += 256) {
        int b = idx / NCHUNK, nn = idx - b * NCHUNK;
        sg[b][nn] = (nn < cnt) ? (g[(size_t)b * NN + n0 + nn] + fb) : 0.f;
    }
    __syncthreads();
    float2 acc[8] = {};
    for (int nn = 0; nn < cnt; ++nn) {
        float2 w = *(const float2*)&W[(size_t)(n0 + nn) * HFC + tid * 2];
        #pragma unroll
        for (int b = 0; b < 8; ++b) {
            float gv = sg[b][nn];
            acc[b].x += gv * w.x;
            acc[b].y += gv * w.y;
        }
    }
    #pragma unroll
    for (int b = 0; b < 8; ++b)
        *(float2*)&zpart[(size_t)ny * 4096 + b * 512 + tid * 2] = acc[b];
}

// ----------------------------- lin1 reduce + lin2 + log_softmax (one launch)
// 8 blocks (one per batch) x 512 threads.
__global__ __launch_bounds__(512)
void k_lin2(const float* __restrict__ zpart, const float* __restrict__ l1b,
            const float* __restrict__ W2, const float* __restrict__ l2b,
            float* __restrict__ out) {
    __shared__ float r0[512], r1[512];
    const int b = blockIdx.x, t = threadIdx.x;
    float s = 0.f;
    for (int c = 0; c < NCHUNKS; ++c) s += zpart[(size_t)c * 4096 + b * 512 + t];
    float zv = s + l1b[t];
    zv = zv > 0.f ? zv : (__expf(zv) - 1.0f);
    r0[t] = zv * W2[t * 2 + 0];
    r1[t] = zv * W2[t * 2 + 1];
    __syncthreads();
    for (int st = 256; st; st >>= 1) {
        if (t < st) { r0[t] += r0[t + st]; r1[t] += r1[t + st]; }
        __syncthreads();
    }
    if (t == 0) {
        float o0 = r0[0] + l2b[0], o1 = r1[0] + l2b[1];
        float m = fmaxf(o0, o1);
        float lse = m + logf(expf(o0 - m) + expf(o1 - m));
        out[b * 2 + 0] = o0 - lse;
        out[b * 2 + 1] = o1 - lse;
    }
}

// ---------------------------------------------------------------- launcher
extern "C" void kernel_launch(void* const* d_in, const int* in_sizes, int n_in,
                              void* d_out, int out_size, void* d_ws, size_t ws_size,
                              hipStream_t stream) {
    const float* x    = (const float*)d_in[0];
    const int*   eidx = (const int*)d_in[2];      // [0..E) = row, [E..2E) = col
    const float* gl   = (const float*)d_in[3];
    const float* W1   = (const float*)d_in[4];
    const float* b1   = (const float*)d_in[5];
    const float* W2   = (const float*)d_in[6];
    const float* b2   = (const float*)d_in[7];
    const float* W3   = (const float*)d_in[8];
    const float* b3   = (const float*)d_in[9];
    const float* fcW  = (const float*)d_in[10];
    const float* fcb  = (const float*)d_in[11];
    const float* l1W  = (const float*)d_in[12];
    const float* l1b  = (const float*)d_in[13];
    const float* l2W  = (const float*)d_in[14];
    const float* l2b  = (const float*)d_in[15];
    float* out = (float*)d_out;

    size_t off = 0;
    auto alloc = [&](size_t bytes) {
        void* p = (char*)d_ws + off;
        off += (bytes + 255) & ~(size_t)255;
        return p;
    };
    bf16* bufA          = (bf16*)alloc((size_t)MPAD * 256 * 2);          // 62 MB
    unsigned char* bufC = (unsigned char*)alloc((size_t)MPAD * 256);     // 31 MB
    bf16* W1T      = (bf16*)alloc(256 * K1P * 2);
    bf16* W2T      = (bf16*)alloc(256 * 256 * 2);
    bf16* W3T      = (bf16*)alloc(256 * 256 * 2);
    int*  deg_cnt  = (int*)alloc(NN * 4);
    int*  offs     = (int*)alloc((NN + 1) * 4);
    int*  cnt2     = (int*)alloc(NN * 4);
    int2* cpack    = (int2*)alloc((size_t)EE * 8);
    float* g       = (float*)alloc((size_t)BSZ * NN * 4);
    int*  sync     = (int*)alloc(1024 * 4);

    // zpart aliases bufC: dead after the last k_agg
    float* zpart = (float*)bufC;                              // 3.9 MB

    const int* erow = eidx;
    const int* ecol = eidx + EE;

    // 1. fused prep (h0, WT x3, zero cnt/cnt2/g/sync)
    k_prep<<<(PREP_TOT + 255) / 256, 256, 0, stream>>>(
        x, gl, bufA, W1, W2, W3, W1T, W2T, W3T, deg_cnt, cnt2, g, sync);

    // 2. fused setup (deg + redundant LDS scan + csr), 1 hierarchical barrier
    k_setup<<<NB_SETUP, TS, 0, stream>>>(erow, ecol, deg_cnt, offs, cnt2,
                                         cpack, sync);

    dim3 ggrid(MPAD / 64);
    dim3 agrid(8 * AGG_GRP);

    // layer 1
    k_gemm<K1P><<<ggrid, 256, 0, stream>>>(bufA, W1T, bufC);
    k_agg<<<agrid, 256, 0, stream>>>(bufC, bufA, offs, cpack,
                                     b1, fcW + 0, g, 1);
    // layer 2
    k_gemm<256><<<ggrid, 256, 0, stream>>>(bufA, W2T, bufC);
    k_agg<<<agrid, 256, 0, stream>>>(bufC, bufA, offs, cpack,
                                     b2, fcW + 1, g, 1);
    // layer 3 (h3 not materialized; only fc contribution)
    k_gemm<256><<<ggrid, 256, 0, stream>>>(bufA, W3T, bufC);
    k_agg<<<agrid, 256, 0, stream>>>(bufC, bufA, offs, cpack,
                                     b3, fcW + 2, g, 0);

    k_lin1<<<NCHUNKS, 256, 0, stream>>>(g, fcb, l1W, zpart);
    k_lin2<<<8, 512, 0, stream>>>(zpart, l1b, l2W, l2b, out);
}

// Round 16
// 438.291 us; speedup vs baseline: 1.0236x; 1.0234x over previous
//
#include <hip/hip_runtime.h>
#include <hip/hip_bf16.h>

using bf16 = __hip_bfloat16;
typedef short s16x8 __attribute__((ext_vector_type(8)));
typedef short s16x4 __attribute__((ext_vector_type(4)));
typedef float f32x4 __attribute__((ext_vector_type(4)));
typedef float f32x2 __attribute__((ext_vector_type(2)));

#define BSZ   8
#define NN    15135
#define FF    64
#define GG    73
#define HH    256
#define EE    242160
#define K1P   160                 // 137 padded to mult of 32 (BK=32 gemm1)
#define MREAL (BSZ * NN)          // 121080
#define MPAD  (946 * 128)         // 121088
#define HFC   512
#define NCHUNK 64
#define NCHUNKS ((NN + NCHUNK - 1) / NCHUNK)   // 237
// fp8 pre-scale: hw stored as e4m3(64*v); x64 folded into WT, 1/64 into csr_norm & dinv
#define FP8_INV_SCALE 0.015625f

#define GLOAD_LDS16(gp, lp)                                                     \
    __builtin_amdgcn_global_load_lds(                                           \
        (const __attribute__((address_space(1))) void*)(gp),                    \
        (__attribute__((address_space(3))) void*)(lp), 16, 0, 0)

// Column permutation applied to the 256-wide GEMM output space.
// Epilogue stores col c at byte position sigma(c) = (c&192) + 4*(c&15) + ((c>>4)&3);
// colmap(p) = sigma^-1(p). Aggregation is element-wise over rows, so a uniform
// column permutation commutes with it; consumers compensate via colmap.
__device__ __forceinline__ int colmap(int p) {
    return (p & 192) | ((p & 3) << 4) | ((p >> 2) & 15);
}

// ------------------------------------------------- fused prep: h0 | WT | zeros
// Zeroes deg counters, csr local counters, g accumulator, sync area.
#define PREP_H0_CNT (MREAL * (K1P / 8))
#define PREP_W1_CNT (256 * K1P)
#define PREP_W23_CNT 65536
#define PREP_TOT (PREP_H0_CNT + PREP_W1_CNT + 2 * PREP_W23_CNT + 2 * NN + MREAL + 1024)
__global__ void k_prep(const float* __restrict__ x, const float* __restrict__ gl,
                       bf16* __restrict__ h0,
                       const float* __restrict__ W1, const float* __restrict__ W2,
                       const float* __restrict__ W3, bf16* __restrict__ W1T,
                       bf16* __restrict__ W2T, bf16* __restrict__ W3T,
                       int* __restrict__ cnt, int* __restrict__ cnt2,
                       float* __restrict__ g, int* __restrict__ sync) {
    int idx = blockIdx.x * blockDim.x + threadIdx.x;
    if (idx < PREP_H0_CNT) {
        int m = idx / (K1P / 8);
        int q = idx - m * (K1P / 8);
        int j0 = q * 8;
        int n = m % NN;
        s16x8 o;
        #pragma unroll
        for (int k = 0; k < 8; ++k) {
            int j = j0 + k;
            float val;
            if (j < FF) val = x[(size_t)m * FF + j];
            else if (j < FF + GG) val = gl[(size_t)n * GG + (j - FF)];
            else val = 0.f;
            o[k] = (short)__bfloat16_as_ushort(__float2bfloat16(val));
        }
        *(s16x8*)&h0[(size_t)m * K1P + j0] = o;
        return;
    }
    idx -= PREP_H0_CNT;
    if (idx < PREP_W1_CNT) {
        int nn = idx / K1P, kk = idx - nn * K1P;
        W1T[idx] = __float2bfloat16(
            kk < FF + GG ? 64.f * W1[(size_t)kk * 256 + nn] : 0.f);
        return;
    }
    idx -= PREP_W1_CNT;
    if (idx < PREP_W23_CNT) {
        int nn = idx >> 8, kk = idx & 255;
        W2T[idx] = __float2bfloat16(64.f * W2[(size_t)colmap(kk) * 256 + nn]);
        return;
    }
    idx -= PREP_W23_CNT;
    if (idx < PREP_W23_CNT) {
        int nn = idx >> 8, kk = idx & 255;
        W3T[idx] = __float2bfloat16(64.f * W3[(size_t)colmap(kk) * 256 + nn]);
        return;
    }
    idx -= PREP_W23_CNT;
    if (idx < NN) { cnt[idx] = 0; return; }
    idx -= NN;
    if (idx < NN) { cnt2[idx] = 0; return; }
    idx -= NN;
    if (idx < MREAL) { g[idx] = 0.f; return; }
    idx -= MREAL;
    if (idx < 1024) sync[idx] = 0;
}

// ------------------------------------------- fused setup: deg+scan+csr
// 240 blocks x 1024 threads; ONE grid barrier (hierarchical: 8 group counters
// on separate cachelines, 30 arrivals each in parallel, then 8 root RMWs --
// the flat 240-RMW-one-line arrive measured ~15us/barrier in R8/R9).
#define NB_SETUP 240
#define TS 1024
__device__ __forceinline__ void gbar_once(int* sync) {
    __syncthreads();
    if (threadIdx.x == 0) {
        __threadfence();
        int grp = blockIdx.x & 7;                     // 30 blocks per group
        int old = atomicAdd(&sync[16 * (grp + 1)], 1);
        if (old == 29) atomicAdd(&sync[0], 1);
        while (__hip_atomic_load(&sync[0], __ATOMIC_RELAXED,
                                 __HIP_MEMORY_SCOPE_AGENT) < 8)
            __builtin_amdgcn_s_sleep(2);
        __threadfence();
    }
    __syncthreads();
}

__global__ __launch_bounds__(1024)
void k_setup(const int* __restrict__ erow, const int* __restrict__ ecol,
             int* __restrict__ cnt, int* __restrict__ offs,
             int* __restrict__ cnt2, int2* __restrict__ cpack,
             int* __restrict__ sync) {
    __shared__ int soffs[NN + 1];                     // 60.5 KB
    __shared__ int wtot[16], wpre[16];
    const int tid = threadIdx.x, bid = blockIdx.x;
    const int gid = bid * TS + tid;
    const int lane = tid & 63, w = tid >> 6;

    // phase 1: histogram; cache edge endpoints for phase 3
    int myc = 0, myr = 0;
    if (gid < EE) {
        myc = ecol[gid];
        myr = erow[gid];
        atomicAdd(&cnt[myc], 1);
    }
    gbar_once(sync);

    // phase 2: block-local exclusive scan of cnt[0..NN] into soffs
    {
        const int base = w * 946;                     // 16*946 = 15136 = NN+1
        int carry = 0;
        #pragma unroll
        for (int j = 0; j < 15; ++j) {                // 15*64=960 >= 946
            int o = j * 64 + lane;
            int i = base + o;
            bool in = o < 946;
            int v = (in && i < NN) ? cnt[i] : 0;
            int s = v;
            #pragma unroll
            for (int off = 1; off < 64; off <<= 1) {
                int t = __shfl_up(s, off);
                if (lane >= off) s += t;
            }
            if (in) soffs[i] = carry + s - v;         // exclusive
            carry += __shfl(s, 63);
        }
        if (lane == 0) wtot[w] = carry;
    }
    __syncthreads();
    if (w == 0 && lane < 16) {
        int t = wtot[lane];
        int s = t;
        #pragma unroll
        for (int off = 1; off < 16; off <<= 1) {
            int u = __shfl_up(s, off);
            if (lane >= off) s += u;
        }
        wpre[lane] = s - t;                           // exclusive over waves
    }
    __syncthreads();
    {
        const int base = w * 946;
        int add = wpre[w];
        if (add) {
            #pragma unroll
            for (int j = 0; j < 15; ++j) {
                int o = j * 64 + lane;
                if (o < 946) soffs[base + o] += add;
            }
        }
    }
    __syncthreads();

    // block 0 publishes offs for k_agg (kernel boundary handles coherence)
    if (bid == 0)
        for (int i = tid; i <= NN; i += TS) offs[i] = soffs[i];

    // phase 3: CSR fill from LDS offsets; norm from degree diffs
    if (gid < EE) {
        int bc = soffs[myc], dc = soffs[myc + 1] - bc;
        int br = soffs[myr], dr = soffs[myr + 1] - br;
        (void)br;
        int p = atomicAdd(&cnt2[myc], 1);
        float norm = rsqrtf((float)(dr + 1)) * rsqrtf((float)(dc + 1))
                     * FP8_INV_SCALE;
        cpack[bc + p] = make_int2(myr, __float_as_int(norm));
    }
}

// -------------------------------------------------- MFMA GEMM, BK=32 (layer 1)
// R10-measured structure: BM=64 x BN=256, 5 gload_lds + 16 MFMA per K-step.
// K1P=160 avoids the 29% zero-padding waste of K=192.
template <int K>
__global__ __launch_bounds__(256)
void k_gemm32(const bf16* __restrict__ A, const bf16* __restrict__ BT,
              unsigned char* __restrict__ C) {
    __shared__ __align__(16) short As[64 * 32];      // 4 KB
    __shared__ __align__(16) short Bs[256 * 32];     // 16 KB
    const int tid  = threadIdx.x;
    const int bm   = blockIdx.x * 64;
    const int lane = tid & 63, wave = tid >> 6;
    const int wn   = wave * 64;
    const int fr   = lane & 15, quad = lane >> 4;
    const int r    = tid >> 2;           // 0..63
    const int c    = (tid & 3) * 8;      // shorts: 0,8,16,24

    const bf16* Ap = A  + (size_t)(bm + r) * K + c;
    const bf16* Bp = BT + (size_t)r * K + c;
    short* AsT = As + tid * 8;
    short* BsT = Bs + tid * 8;

    f32x4 acc[4][4] = {};

    for (int k0 = 0; k0 < K; k0 += 32) {
        GLOAD_LDS16(Ap + k0, AsT);
        #pragma unroll
        for (int q = 0; q < 4; ++q)
            GLOAD_LDS16(Bp + (size_t)(q * 64) * K + k0, BsT + q * 64 * 32);
        __syncthreads();
        s16x8 af[4], bfv[4];
        #pragma unroll
        for (int i = 0; i < 4; ++i)
            af[i] = *(const s16x8*)&As[(i * 16 + fr) * 32 + quad * 8];
        #pragma unroll
        for (int j = 0; j < 4; ++j)
            bfv[j] = *(const s16x8*)&Bs[(wn + j * 16 + fr) * 32 + quad * 8];
        #pragma unroll
        for (int i = 0; i < 4; ++i)
            #pragma unroll
            for (int j = 0; j < 4; ++j)
                acc[i][j] = __builtin_amdgcn_mfma_f32_16x16x32_bf16(
                    af[i], bfv[j], acc[i][j], 0, 0, 0);
        __syncthreads();
    }

    #pragma unroll
    for (int i = 0; i < 4; ++i) {
        int rbase = bm + i * 16 + quad * 4;
        #pragma unroll
        for (int rr = 0; rr < 4; ++rr) {
            int row = rbase + rr;
            if (row >= MREAL) continue;
            unsigned wpack = (unsigned)__builtin_amdgcn_cvt_pk_fp8_f32(
                acc[i][0][rr], acc[i][1][rr], 0, false);
            wpack = (unsigned)__builtin_amdgcn_cvt_pk_fp8_f32(
                acc[i][2][rr], acc[i][3][rr], (int)wpack, true);
            *(unsigned*)&C[(size_t)row * 256 + wn + fr * 4] = wpack;
        }
    }
}

// -------------------------------------------- MFMA GEMM, BK=64 (layers 2/3)
// R13-measured twin-buffer structure: 32 MFMA per barrier pair.
template <int K>
__global__ __launch_bounds__(256)
void k_gemm64(const bf16* __restrict__ A, const bf16* __restrict__ BT,
              unsigned char* __restrict__ C) {
    __shared__ __align__(16) short As0[64 * 32], As1[64 * 32];    // 4+4 KB
    __shared__ __align__(16) short Bs0[256 * 32], Bs1[256 * 32];  // 16+16 KB
    const int tid  = threadIdx.x;
    const int bm   = blockIdx.x * 64;
    const int lane = tid & 63, wave = tid >> 6;
    const int wn   = wave * 64;
    const int fr   = lane & 15, quad = lane >> 4;
    const int r    = tid >> 2;           // 0..63
    const int c    = (tid & 3) * 8;      // shorts: 0,8,16,24

    const bf16* Ap = A  + (size_t)(bm + r) * K + c;
    const bf16* Bp = BT + (size_t)r * K + c;
    short* As0T = As0 + tid * 8;
    short* As1T = As1 + tid * 8;
    short* Bs0T = Bs0 + tid * 8;
    short* Bs1T = Bs1 + tid * 8;

    f32x4 acc[4][4] = {};

    for (int k0 = 0; k0 < K; k0 += 64) {
        GLOAD_LDS16(Ap + k0,      As0T);
        GLOAD_LDS16(Ap + k0 + 32, As1T);
        #pragma unroll
        for (int q = 0; q < 4; ++q) {
            GLOAD_LDS16(Bp + (size_t)(q * 64) * K + k0,      Bs0T + q * 64 * 32);
            GLOAD_LDS16(Bp + (size_t)(q * 64) * K + k0 + 32, Bs1T + q * 64 * 32);
        }
        __syncthreads();
        {
            s16x8 af[4], bfv[4];
            #pragma unroll
            for (int i = 0; i < 4; ++i)
                af[i] = *(const s16x8*)&As0[(i * 16 + fr) * 32 + quad * 8];
            #pragma unroll
            for (int j = 0; j < 4; ++j)
                bfv[j] = *(const s16x8*)&Bs0[(wn + j * 16 + fr) * 32 + quad * 8];
            #pragma unroll
            for (int i = 0; i < 4; ++i)
                #pragma unroll
                for (int j = 0; j < 4; ++j)
                    acc[i][j] = __builtin_amdgcn_mfma_f32_16x16x32_bf16(
                        af[i], bfv[j], acc[i][j], 0, 0, 0);
        }
        {
            s16x8 af[4], bfv[4];
            #pragma unroll
            for (int i = 0; i < 4; ++i)
                af[i] = *(const s16x8*)&As1[(i * 16 + fr) * 32 + quad * 8];
            #pragma unroll
            for (int j = 0; j < 4; ++j)
                bfv[j] = *(const s16x8*)&Bs1[(wn + j * 16 + fr) * 32 + quad * 8];
            #pragma unroll
            for (int i = 0; i < 4; ++i)
                #pragma unroll
                for (int j = 0; j < 4; ++j)
                    acc[i][j] = __builtin_amdgcn_mfma_f32_16x16x32_bf16(
                        af[i], bfv[j], acc[i][j], 0, 0, 0);
        }
        __syncthreads();
    }

    #pragma unroll
    for (int i = 0; i < 4; ++i) {
        int rbase = bm + i * 16 + quad * 4;
        #pragma unroll
        for (int rr = 0; rr < 4; ++rr) {
            int row = rbase + rr;
            if (row >= MREAL) continue;
            unsigned wpack = (unsigned)__builtin_amdgcn_cvt_pk_fp8_f32(
                acc[i][0][rr], acc[i][1][rr], 0, false);
            wpack = (unsigned)__builtin_amdgcn_cvt_pk_fp8_f32(
                acc[i][2][rr], acc[i][3][rr], (int)wpack, true);
            *(unsigned*)&C[(size_t)row * 256 + wn + fr * 4] = wpack;
        }
    }
}

// ------------------------------------------------------- aggregate + elu + fc
// R13-measured best config (AGG_GRP 1024; dual-node & finer-grain both
// regressed). hout NON-TEMPORAL; batch-partitioned per XCD; scalar metadata.
#define AGG_GRP 1024
#define AGG_STRIDE (AGG_GRP * 4)          // 4096 waves per batch
__global__ __launch_bounds__(256, 8)
void k_agg(const unsigned char* __restrict__ hw, bf16* __restrict__ hout,
           const int* __restrict__ offs, const int2* __restrict__ cpack,
           const float* __restrict__ bias, const float* __restrict__ fcW,
           float* __restrict__ g, int writeH) {
    const int b    = blockIdx.x & 7;
    const int grp  = blockIdx.x >> 3;          // 0..AGG_GRP-1
    const int wid  = threadIdx.x >> 6;         // 0..3
    const int lane = threadIdx.x & 63;
    const int wv   = grp * 4 + wid;            // 0..AGG_STRIDE-1
    const unsigned c4 = lane * 4;

    const unsigned char* hwb = hw + (size_t)b * NN * 256;

    float bias4[4], fw4[4];
    #pragma unroll
    for (int k = 0; k < 4; ++k) {
        int cl = colmap((int)c4 + k);
        bias4[k] = bias[cl];
        fw4[k]   = fcW[3 * cl];
    }

    for (int v0 = wv; v0 < NN; v0 += AGG_STRIDE) {
        const int v   = __builtin_amdgcn_readfirstlane(v0);
        const int beg = __builtin_amdgcn_readfirstlane(offs[v]);
        const int end = __builtin_amdgcn_readfirstlane(offs[v + 1]);
        const float di = FP8_INV_SCALE / (float)(end - beg + 1);
        f32x2 a01, a23;
        {
            unsigned q = *(const unsigned*)(hwb + (((unsigned)v) << 8) + c4);
            f32x2 t0 = __builtin_amdgcn_cvt_pk_f32_fp8(q, false);
            f32x2 t1 = __builtin_amdgcn_cvt_pk_f32_fp8(q, true);
            f32x2 dd = {di, di};
            a01 = dd * t0;
            a23 = dd * t1;
        }

        #define EDGE1(qv, mv) {                                            \
            f32x2 t0 = __builtin_amdgcn_cvt_pk_f32_fp8((qv), false);       \
            f32x2 t1 = __builtin_amdgcn_cvt_pk_f32_fp8((qv), true);        \
            f32x2 mm = {(mv), (mv)};                                       \
            a01 += mm * t0;                                                \
            a23 += mm * t1; }

        int e = beg;
        while (e + 16 <= end) {
            int2 ep[16];
            #pragma unroll
            for (int u = 0; u < 16; ++u) ep[u] = cpack[e + u];
            unsigned q[16];
            #pragma unroll
            for (int u = 0; u < 16; ++u)
                q[u] = *(const unsigned*)(hwb + (((unsigned)ep[u].x) << 8) + c4);
            #pragma unroll
            for (int u = 0; u < 16; ++u) EDGE1(q[u], __int_as_float(ep[u].y));
            e += 16;
        }
        if (e + 8 <= end) {
            int2 ep[8];
            #pragma unroll
            for (int u = 0; u < 8; ++u) ep[u] = cpack[e + u];
            unsigned q[8];
            #pragma unroll
            for (int u = 0; u < 8; ++u)
                q[u] = *(const unsigned*)(hwb + (((unsigned)ep[u].x) << 8) + c4);
            #pragma unroll
            for (int u = 0; u < 8; ++u) EDGE1(q[u], __int_as_float(ep[u].y));
            e += 8;
        }
        if (e + 4 <= end) {
            int2 ep[4];
            #pragma unroll
            for (int u = 0; u < 4; ++u) ep[u] = cpack[e + u];
            unsigned q[4];
            #pragma unroll
            for (int u = 0; u < 4; ++u)
                q[u] = *(const unsigned*)(hwb + (((unsigned)ep[u].x) << 8) + c4);
            #pragma unroll
            for (int u = 0; u < 4; ++u) EDGE1(q[u], __int_as_float(ep[u].y));
            e += 4;
        }
        if (e + 2 <= end) {
            int2 ep0 = cpack[e], ep1 = cpack[e + 1];
            unsigned q0 = *(const unsigned*)(hwb + (((unsigned)ep0.x) << 8) + c4);
            unsigned q1 = *(const unsigned*)(hwb + (((unsigned)ep1.x) << 8) + c4);
            EDGE1(q0, __int_as_float(ep0.y));
            EDGE1(q1, __int_as_float(ep1.y));
            e += 2;
        }
        if (e < end) {
            int2 ep0 = cpack[e];
            unsigned q0 = *(const unsigned*)(hwb + (((unsigned)ep0.x) << 8) + c4);
            EDGE1(q0, __int_as_float(ep0.y));
        }
        #undef EDGE1

        float acc4[4] = {a01[0], a01[1], a23[0], a23[1]};
        float p = 0.f;
        s16x4 o4;
        #pragma unroll
        for (int k = 0; k < 4; ++k) {
            float hv = acc4[k] + bias4[k];
            hv = hv > 0.f ? hv : (__expf(hv) - 1.0f);
            o4[k] = (short)__bfloat16_as_ushort(__float2bfloat16(hv));
            p += hv * fw4[k];
        }
        if (writeH) {
            s16x4* dst = (s16x4*)&hout[((size_t)b * NN + v) * 256 + c4];
            __builtin_nontemporal_store(o4, dst);
        }

        #pragma unroll
        for (int off = 32; off; off >>= 1) p += __shfl_xor(p, off);
        if (lane == 0) g[(size_t)b * NN + v] += p;
    }
}

// ------------------------------------------------------------ lin1 partials
__global__ __launch_bounds__(256)
void k_lin1(const float* __restrict__ g, const float* __restrict__ fcb,
            const float* __restrict__ W, float* __restrict__ zpart) {
    const int ny = blockIdx.x;
    const int n0 = ny * NCHUNK;
    const int cnt = min(NCHUNK, NN - n0);
    const int tid = threadIdx.x;
    __shared__ float sg[8][NCHUNK];
    float fb = fcb[0];
    for (int idx = tid; idx < 8 * NCHUNK; idx += 256) {
        int b = idx / NCHUNK, nn = idx - b * NCHUNK;
        sg[b][nn] = (nn < cnt) ? (g[(size_t)b * NN + n0 + nn] + fb) : 0.f;
    }
    __syncthreads();
    float2 acc[8] = {};
    for (int nn = 0; nn < cnt; ++nn) {
        float2 w = *(const float2*)&W[(size_t)(n0 + nn) * HFC + tid * 2];
        #pragma unroll
        for (int b = 0; b < 8; ++b) {
            float gv = sg[b][nn];
            acc[b].x += gv * w.x;
            acc[b].y += gv * w.y;
        }
    }
    #pragma unroll
    for (int b = 0; b < 8; ++b)
        *(float2*)&zpart[(size_t)ny * 4096 + b * 512 + tid * 2] = acc[b];
}

// ----------------------------- lin1 reduce + lin2 + log_softmax (one launch)
__global__ __launch_bounds__(512)
void k_lin2(const float* __restrict__ zpart, const float* __restrict__ l1b,
            const float* __restrict__ W2, const float* __restrict__ l2b,
            float* __restrict__ out) {
    __shared__ float r0[512], r1[512];
    const int b = blockIdx.x, t = threadIdx.x;
    float s = 0.f;
    for (int c = 0; c < NCHUNKS; ++c) s += zpart[(size_t)c * 4096 + b * 512 + t];
    float zv = s + l1b[t];
    zv = zv > 0.f ? zv : (__expf(zv) - 1.0f);
    r0[t] = zv * W2[t * 2 + 0];
    r1[t] = zv * W2[t * 2 + 1];
    __syncthreads();
    for (int st = 256; st; st >>= 1) {
        if (t < st) { r0[t] += r0[t + st]; r1[t] += r1[t + st]; }
        __syncthreads();
    }
    if (t == 0) {
        float o0 = r0[0] + l2b[0], o1 = r1[0] + l2b[1];
        float m = fmaxf(o0, o1);
        float lse = m + logf(expf(o0 - m) + expf(o1 - m));
        out[b * 2 + 0] = o0 - lse;
        out[b * 2 + 1] = o1 - lse;
    }
}

// ---------------------------------------------------------------- launcher
extern "C" void kernel_launch(void* const* d_in, const int* in_sizes, int n_in,
                              void* d_out, int out_size, void* d_ws, size_t ws_size,
                              hipStream_t stream) {
    const float* x    = (const float*)d_in[0];
    const int*   eidx = (const int*)d_in[2];      // [0..E) = row, [E..2E) = col
    const float* gl   = (const float*)d_in[3];
    const float* W1   = (const float*)d_in[4];
    const float* b1   = (const float*)d_in[5];
    const float* W2   = (const float*)d_in[6];
    const float* b2   = (const float*)d_in[7];
    const float* W3   = (const float*)d_in[8];
    const float* b3   = (const float*)d_in[9];
    const float* fcW  = (const float*)d_in[10];
    const float* fcb  = (const float*)d_in[11];
    const float* l1W  = (const float*)d_in[12];
    const float* l1b  = (const float*)d_in[13];
    const float* l2W  = (const float*)d_in[14];
    const float* l2b  = (const float*)d_in[15];
    float* out = (float*)d_out;

    size_t off = 0;
    auto alloc = [&](size_t bytes) {
        void* p = (char*)d_ws + off;
        off += (bytes + 255) & ~(size_t)255;
        return p;
    };
    bf16* bufA          = (bf16*)alloc((size_t)MPAD * 256 * 2);          // 62 MB
    unsigned char* bufC = (unsigned char*)alloc((size_t)MPAD * 256);     // 31 MB
    bf16* W1T      = (bf16*)alloc(256 * K1P * 2);
    bf16* W2T      = (bf16*)alloc(256 * 256 * 2);
    bf16* W3T      = (bf16*)alloc(256 * 256 * 2);
    int*  deg_cnt  = (int*)alloc(NN * 4);
    int*  offs     = (int*)alloc((NN + 1) * 4);
    int*  cnt2     = (int*)alloc(NN * 4);
    int2* cpack    = (int2*)alloc((size_t)EE * 8);
    float* g       = (float*)alloc((size_t)BSZ * NN * 4);
    int*  sync     = (int*)alloc(1024 * 4);

    // zpart aliases bufC: dead after the last k_agg
    float* zpart = (float*)bufC;                              // 3.9 MB

    const int* erow = eidx;
    const int* ecol = eidx + EE;

    // 1. fused prep (h0, WT x3, zero cnt/cnt2/g/sync)
    k_prep<<<(PREP_TOT + 255) / 256, 256, 0, stream>>>(
        x, gl, bufA, W1, W2, W3, W1T, W2T, W3T, deg_cnt, cnt2, g, sync);

    // 2. fused setup (deg + redundant LDS scan + csr), 1 hierarchical barrier
    k_setup<<<NB_SETUP, TS, 0, stream>>>(erow, ecol, deg_cnt, offs, cnt2,
                                         cpack, sync);

    dim3 ggrid(MPAD / 64);
    dim3 agrid(8 * AGG_GRP);

    // layer 1 (BK=32, K=160: no zero-pad waste)
    k_gemm32<K1P><<<ggrid, 256, 0, stream>>>(bufA, W1T, bufC);
    k_agg<<<agrid, 256, 0, stream>>>(bufC, bufA, offs, cpack,
                                     b1, fcW + 0, g, 1);
    // layer 2 (BK=64 twin)
    k_gemm64<256><<<ggrid, 256, 0, stream>>>(bufA, W2T, bufC);
    k_agg<<<agrid, 256, 0, stream>>>(bufC, bufA, offs, cpack,
                                     b2, fcW + 1, g, 1);
    // layer 3 (h3 not materialized; only fc contribution)
    k_gemm64<256><<<ggrid, 256, 0, stream>>>(bufA, W3T, bufC);
    k_agg<<<agrid, 256, 0, stream>>>(bufC, bufA, offs, cpack,
                                     b3, fcW + 2, g, 0);

    k_lin1<<<NCHUNKS, 256, 0, stream>>>(g, fcb, l1W, zpart);
    k_lin2<<<8, 512, 0, stream>>>(zpart, l1b, l2W, l2b, out);
}